// Round 1
// baseline (2347.583 us; speedup 1.0000x reference)
//
#include <hip/hip_runtime.h>

#define N_NODES 200000
#define N_EDGES 1200000
#define F_IN    64
#define F_H     128
#define BN_EPS  1e-5f

// ---------------------------------------------------------------------------
// Scatter-add aggregation: agg[dst] += x[src], one thread per (edge, feature).
// Within a wave, consecutive lanes = consecutive features of the same edge ->
// coalesced reads and coalesced (conflict-free) atomics.
// ---------------------------------------------------------------------------
template<int F>
__global__ __launch_bounds__(256) void scatter_add_kernel(
    const float* __restrict__ x, const int* __restrict__ ei,
    float* __restrict__ agg, int E)
{
    int idx = blockIdx.x * 256 + threadIdx.x;
    if (idx >= E * F) return;
    int e = idx >> (F == 64 ? 6 : 7);
    int f = idx & (F - 1);
    int s = ei[e];          // src
    int d = ei[E + e];      // dst
    atomicAdd(&agg[(size_t)d * F + f], x[(size_t)s * F + f]);
}

// ---------------------------------------------------------------------------
// out[row, :] = relu(A[row,:] @ Wl + bias + X[row,:] @ Wr)   (128 output cols)
// Fused BN-stats: per-feature sum and sum-of-squares accumulated via
// per-thread registers -> LDS -> one global atomic per feature per block.
// Thread layout: c4 = tid&31 (float4 col group), rl = tid>>5 (row in 8-row tile),
// grid-strided over row tiles.
// ---------------------------------------------------------------------------
template<int K>
__global__ __launch_bounds__(256) void gemm_relu_stats_kernel(
    const float* __restrict__ A, const float* __restrict__ X,
    const float* __restrict__ Wl, const float* __restrict__ Wr,
    const float* __restrict__ bias,
    float* __restrict__ out,
    float* __restrict__ gsum, float* __restrict__ gsq,
    int N)
{
    const int tid = threadIdx.x;
    const int c4  = tid & 31;   // which float4 of the 128 cols
    const int rl  = tid >> 5;   // 0..7 local row

    const float4 bb = ((const float4*)bias)[c4];
    float4 psum = {0.f, 0.f, 0.f, 0.f};
    float4 psq  = {0.f, 0.f, 0.f, 0.f};

    for (int row = blockIdx.x * 8 + rl; row < N; row += gridDim.x * 8) {
        float4 acc = bb;
        const float4* a4 = (const float4*)(A + (size_t)row * K);
        const float4* x4 = (const float4*)(X + (size_t)row * K);
        for (int k4 = 0; k4 < K / 4; ++k4) {
            float4 av = a4[k4];
            float4 xv = x4[k4];
            const float* avp = (const float*)&av;
            const float* xvp = (const float*)&xv;
#pragma unroll
            for (int j = 0; j < 4; ++j) {
                int k = k4 * 4 + j;
                float4 w1 = *(const float4*)(Wl + (size_t)k * 128 + c4 * 4);
                float4 w2 = *(const float4*)(Wr + (size_t)k * 128 + c4 * 4);
                float a = avp[j], xs = xvp[j];
                acc.x = fmaf(a, w1.x, acc.x); acc.y = fmaf(a, w1.y, acc.y);
                acc.z = fmaf(a, w1.z, acc.z); acc.w = fmaf(a, w1.w, acc.w);
                acc.x = fmaf(xs, w2.x, acc.x); acc.y = fmaf(xs, w2.y, acc.y);
                acc.z = fmaf(xs, w2.z, acc.z); acc.w = fmaf(xs, w2.w, acc.w);
            }
        }
        acc.x = fmaxf(acc.x, 0.f); acc.y = fmaxf(acc.y, 0.f);
        acc.z = fmaxf(acc.z, 0.f); acc.w = fmaxf(acc.w, 0.f);
        *(float4*)(out + (size_t)row * 128 + c4 * 4) = acc;
        psum.x += acc.x; psum.y += acc.y; psum.z += acc.z; psum.w += acc.w;
        psq.x  = fmaf(acc.x, acc.x, psq.x); psq.y = fmaf(acc.y, acc.y, psq.y);
        psq.z  = fmaf(acc.z, acc.z, psq.z); psq.w = fmaf(acc.w, acc.w, psq.w);
    }

    __shared__ float sSum[128];
    __shared__ float sSq[128];
    if (tid < 128) { sSum[tid] = 0.f; sSq[tid] = 0.f; }
    __syncthreads();
    int c = c4 * 4;
    atomicAdd(&sSum[c + 0], psum.x); atomicAdd(&sSum[c + 1], psum.y);
    atomicAdd(&sSum[c + 2], psum.z); atomicAdd(&sSum[c + 3], psum.w);
    atomicAdd(&sSq[c + 0], psq.x);   atomicAdd(&sSq[c + 1], psq.y);
    atomicAdd(&sSq[c + 2], psq.z);   atomicAdd(&sSq[c + 3], psq.w);
    __syncthreads();
    if (tid < 128)       atomicAdd(&gsum[tid], sSum[tid]);
    else                 atomicAdd(&gsq[tid - 128], sSq[tid - 128]);
}

// ---------------------------------------------------------------------------
// BN finalize: per-feature scale/shift from accumulated sum/sumsq.
// ---------------------------------------------------------------------------
__global__ void bn_finalize_kernel(
    const float* __restrict__ gsum, const float* __restrict__ gsq,
    const float* __restrict__ g, const float* __restrict__ be,
    float* __restrict__ scale, float* __restrict__ shift, float invN)
{
    int c = threadIdx.x;  // 128 threads
    float mean = gsum[c] * invN;
    float var  = fmaxf(gsq[c] * invN - mean * mean, 0.f);
    float sc   = g[c] * rsqrtf(var + BN_EPS);
    scale[c] = sc;
    shift[c] = be[c] - mean * sc;
}

// ---------------------------------------------------------------------------
// BN apply (in place), optional trailing ReLU. Vectorized float4.
// ---------------------------------------------------------------------------
template<bool RELU>
__global__ __launch_bounds__(256) void bn_apply_kernel(
    float* __restrict__ h, const float* __restrict__ scale,
    const float* __restrict__ shift, int n4)
{
    int i = blockIdx.x * 256 + threadIdx.x;
    if (i >= n4) return;
    int cb = i & 31;  // col float4 index (row-major, 128 cols = 32 float4)
    float4 v  = ((float4*)h)[i];
    float4 sc = ((const float4*)scale)[cb];
    float4 sh = ((const float4*)shift)[cb];
    v.x = fmaf(v.x, sc.x, sh.x); v.y = fmaf(v.y, sc.y, sh.y);
    v.z = fmaf(v.z, sc.z, sh.z); v.w = fmaf(v.w, sc.w, sh.w);
    if (RELU) {
        v.x = fmaxf(v.x, 0.f); v.y = fmaxf(v.y, 0.f);
        v.z = fmaxf(v.z, 0.f); v.w = fmaxf(v.w, 0.f);
    }
    ((float4*)h)[i] = v;
}

extern "C" void kernel_launch(void* const* d_in, const int* in_sizes, int n_in,
                              void* d_out, int out_size, void* d_ws, size_t ws_size,
                              hipStream_t stream) {
    const float* x   = (const float*)d_in[0];
    const int*   ei  = (const int*)d_in[1];   // [2, E] int32
    const float* W1l = (const float*)d_in[2];
    const float* b1  = (const float*)d_in[3];
    const float* W1r = (const float*)d_in[4];
    const float* g1  = (const float*)d_in[5];
    const float* be1 = (const float*)d_in[6];
    const float* W2l = (const float*)d_in[7];
    const float* b2  = (const float*)d_in[8];
    const float* W2r = (const float*)d_in[9];
    const float* g2  = (const float*)d_in[10];
    const float* be2 = (const float*)d_in[11];
    float* out = (float*)d_out;

    const int N = N_NODES, E = N_EDGES;

    // Workspace layout (floats):
    // [0..1024)           stats: gsum1,gsq1,gsum2,gsq2,scale1,shift1,scale2,shift2
    // [1024 .. +N*128)    R1: agg1 (first N*64) then reused as agg2 (N*128)
    // [.. +N*128)         t1/h1
    float* ws     = (float*)d_ws;
    float* gsum1  = ws;        float* gsq1   = ws + 128;
    float* gsum2  = ws + 256;  float* gsq2   = ws + 384;
    float* scale1 = ws + 512;  float* shift1 = ws + 640;
    float* scale2 = ws + 768;  float* shift2 = ws + 896;
    float* R1 = ws + 1024;
    float* t1 = R1 + (size_t)N * F_H;
    float* agg1 = R1;
    float* agg2 = R1;

    // ---- Layer 1 ----
    // zero stats + agg1
    hipMemsetAsync(ws, 0, (1024 + (size_t)N * F_IN) * sizeof(float), stream);
    {
        int total = E * F_IN;
        scatter_add_kernel<F_IN><<<(total + 255) / 256, 256, 0, stream>>>(x, ei, agg1, E);
    }
    gemm_relu_stats_kernel<F_IN><<<2048, 256, 0, stream>>>(
        agg1, x, W1l, W1r, b1, t1, gsum1, gsq1, N);
    bn_finalize_kernel<<<1, 128, 0, stream>>>(gsum1, gsq1, g1, be1, scale1, shift1, 1.f / N);
    {
        int n4 = N * F_H / 4;
        bn_apply_kernel<false><<<(n4 + 255) / 256, 256, 0, stream>>>(t1, scale1, shift1, n4);
    }

    // ---- Layer 2 ----
    hipMemsetAsync(agg2, 0, (size_t)N * F_H * sizeof(float), stream);
    {
        int total = E * F_H;
        scatter_add_kernel<F_H><<<(total + 255) / 256, 256, 0, stream>>>(t1, ei, agg2, E);
    }
    gemm_relu_stats_kernel<F_H><<<2048, 256, 0, stream>>>(
        agg2, t1, W2l, W2r, b2, out, gsum2, gsq2, N);
    bn_finalize_kernel<<<1, 128, 0, stream>>>(gsum2, gsq2, g2, be2, scale2, shift2, 1.f / N);
    {
        int n4 = N * F_H / 4;
        bn_apply_kernel<true><<<(n4 + 255) / 256, 256, 0, stream>>>(out, scale2, shift2, n4);
    }
}

// Round 2
// 1238.966 us; speedup vs baseline: 1.8948x; 1.8948x over previous
//
#include <hip/hip_runtime.h>

#define N_NODES 200000
#define N_EDGES 1200000
#define F_IN    64
#define F_H     128
#define BN_EPS  1e-5f

typedef short bf16x8 __attribute__((ext_vector_type(8)));   // 8 bf16 in 4 VGPRs
typedef float f32x4  __attribute__((ext_vector_type(4)));

__device__ __forceinline__ short f2bf(float f) {
    union { float f; unsigned u; } v; v.f = f;
    unsigned r = (v.u + 0x7FFFu + ((v.u >> 16) & 1u)) >> 16;  // RNE
    return (short)r;
}

// ---------------------------------------------------------------------------
// Pack a [K,128] fp32 weight matrix into bf16 MFMA B-fragment order for
// mfma_f32_16x16x32_bf16: element j of lane L in (nt,kt) tile is
// B[kt*32 + (L>>4)*8 + j][nt*16 + (L&15)].
// Linear: P[((nt*KT + kt)*64 + lane)*8 + j]
// ---------------------------------------------------------------------------
__global__ void pack_weights_kernel(const float* __restrict__ W,
                                    short* __restrict__ P, int KT)
{
    int t = blockIdx.x * 256 + threadIdx.x;            // over 8*KT*64
    if (t >= 8 * KT * 64) return;
    int lane = t & 63;
    int kt   = (t >> 6) % KT;
    int nt   = t / (64 * KT);
    int k0   = kt * 32 + (lane >> 4) * 8;
    int n    = nt * 16 + (lane & 15);
#pragma unroll
    for (int j = 0; j < 8; ++j)
        P[(size_t)t * 8 + j] = f2bf(W[(size_t)(k0 + j) * 128 + n]);
}

// ---------------------------------------------------------------------------
// Scatter-add aggregation (layer 1): agg[dst] += x[src]
// ---------------------------------------------------------------------------
__global__ __launch_bounds__(256) void scatter_add_kernel(
    const float* __restrict__ x, const int* __restrict__ ei,
    float* __restrict__ agg, int E)
{
    int idx = blockIdx.x * 256 + threadIdx.x;
    if (idx >= E * F_IN) return;
    int e = idx >> 6;
    int f = idx & 63;
    int s = ei[e];
    int d = ei[E + e];
    atomicAdd(&agg[(size_t)d * F_IN + f], x[(size_t)s * F_IN + f]);
}

// ---------------------------------------------------------------------------
// Scatter-add with fused BN1 apply (layer 2): agg[dst] += bn1(t1[src])
// ---------------------------------------------------------------------------
__global__ __launch_bounds__(256) void scatter_add_bn_kernel(
    const float* __restrict__ t1, const int* __restrict__ ei,
    const float* __restrict__ scale, const float* __restrict__ shift,
    float* __restrict__ agg, int E)
{
    int idx = blockIdx.x * 256 + threadIdx.x;
    if (idx >= E * F_H) return;
    int e = idx >> 7;
    int f = idx & 127;
    int s = ei[e];
    int d = ei[E + e];
    float v = fmaf(t1[(size_t)s * F_H + f], scale[f], shift[f]);
    atomicAdd(&agg[(size_t)d * F_H + f], v);
}

// ---------------------------------------------------------------------------
// MFMA GEMM: out[row,:] = relu(A[row,:]@Wl + bias + bnX(X[row,:])@Wr), 128 cols.
// bf16 mfma_f32_16x16x32. Block = 256 thr = 4 waves; wave = 16 rows x 128 cols
// (8 n-tiles, acc = 8 x f32x4 = 32 VGPR). Weights pre-packed in fragment order,
// loaded as one b128 per lane per tile from global (L1/L2 resident, 64 KB).
// A/X rows loaded fp32 directly in A-fragment layout (lane&15 = row,
// lane>>4 selects 8-wide k chunk) and converted to bf16 in-register.
// Fused BN stats (sum, sumsq of relu'd output) via LDS -> 1 atomic/col/block.
// N must be divisible by 64 (200000 = 3125*64).
// ---------------------------------------------------------------------------
template<int K, bool BNX>
__global__ __launch_bounds__(256) void gemm_mfma_kernel(
    const float* __restrict__ A, const float* __restrict__ X,
    const short* __restrict__ Wlp, const short* __restrict__ Wrp,
    const float* __restrict__ bias,
    const float* __restrict__ scx, const float* __restrict__ shx,
    float* __restrict__ out, float* __restrict__ gsum, float* __restrict__ gsq)
{
    constexpr int KT = K / 32;
    __shared__ float sS[128];
    __shared__ float sQ[128];

    const int tid  = threadIdx.x;
    const int lane = tid & 63;
    const int wv   = tid >> 6;
    const int m    = lane & 15;
    const int quad = lane >> 4;
    const int rowbase = blockIdx.x * 64 + wv * 16;
    const int row  = rowbase + m;

    if (tid < 128) { sS[tid] = 0.f; sQ[tid] = 0.f; }

    f32x4 acc[8] = {};

#pragma unroll
    for (int kt = 0; kt < KT; ++kt) {
        const int k0 = kt * 32 + quad * 8;
        const float4* ap = (const float4*)(A + (size_t)row * K + k0);
        const float4* xp = (const float4*)(X + (size_t)row * K + k0);
        float4 a0 = ap[0], a1 = ap[1];
        float4 x0 = xp[0], x1 = xp[1];
        if constexpr (BNX) {
            float4 s0 = *(const float4*)(scx + k0), s1 = *(const float4*)(scx + k0 + 4);
            float4 h0 = *(const float4*)(shx + k0), h1 = *(const float4*)(shx + k0 + 4);
            x0.x = fmaf(x0.x, s0.x, h0.x); x0.y = fmaf(x0.y, s0.y, h0.y);
            x0.z = fmaf(x0.z, s0.z, h0.z); x0.w = fmaf(x0.w, s0.w, h0.w);
            x1.x = fmaf(x1.x, s1.x, h1.x); x1.y = fmaf(x1.y, s1.y, h1.y);
            x1.z = fmaf(x1.z, s1.z, h1.z); x1.w = fmaf(x1.w, s1.w, h1.w);
        }
        bf16x8 af, xf;
        af[0] = f2bf(a0.x); af[1] = f2bf(a0.y); af[2] = f2bf(a0.z); af[3] = f2bf(a0.w);
        af[4] = f2bf(a1.x); af[5] = f2bf(a1.y); af[6] = f2bf(a1.z); af[7] = f2bf(a1.w);
        xf[0] = f2bf(x0.x); xf[1] = f2bf(x0.y); xf[2] = f2bf(x0.z); xf[3] = f2bf(x0.w);
        xf[4] = f2bf(x1.x); xf[5] = f2bf(x1.y); xf[6] = f2bf(x1.z); xf[7] = f2bf(x1.w);

#pragma unroll
        for (int nt = 0; nt < 8; ++nt) {
            bf16x8 wl = *(const bf16x8*)(Wlp + ((size_t)(nt * KT + kt) * 64 + lane) * 8);
            acc[nt] = __builtin_amdgcn_mfma_f32_16x16x32_bf16(af, wl, acc[nt], 0, 0, 0);
            bf16x8 wr = *(const bf16x8*)(Wrp + ((size_t)(nt * KT + kt) * 64 + lane) * 8);
            acc[nt] = __builtin_amdgcn_mfma_f32_16x16x32_bf16(xf, wr, acc[nt], 0, 0, 0);
        }
    }

    __syncthreads();   // sS/sQ init done

    // C/D layout (m89-verified): col = lane&15, row = quad*4 + reg
    const int col_l = lane & 15;
    const int orow  = rowbase + quad * 4;
#pragma unroll
    for (int nt = 0; nt < 8; ++nt) {
        int col = nt * 16 + col_l;
        float b = bias[col];
        float s = 0.f, q = 0.f;
#pragma unroll
        for (int r = 0; r < 4; ++r) {
            float v = fmaxf(acc[nt][r] + b, 0.f);
            out[(size_t)(orow + r) * 128 + col] = v;
            s += v;
            q = fmaf(v, v, q);
        }
        atomicAdd(&sS[col], s);
        atomicAdd(&sQ[col], q);
    }
    __syncthreads();
    if (tid < 128) {
        atomicAdd(&gsum[tid], sS[tid]);
        atomicAdd(&gsq[tid],  sQ[tid]);
    }
}

// ---------------------------------------------------------------------------
// BN finalize: per-feature scale/shift from accumulated sum/sumsq.
// ---------------------------------------------------------------------------
__global__ void bn_finalize_kernel(
    const float* __restrict__ gsum, const float* __restrict__ gsq,
    const float* __restrict__ g, const float* __restrict__ be,
    float* __restrict__ scale, float* __restrict__ shift, float invN)
{
    int c = threadIdx.x;  // 128 threads
    float mean = gsum[c] * invN;
    float var  = fmaxf(gsq[c] * invN - mean * mean, 0.f);
    float sc   = g[c] * rsqrtf(var + BN_EPS);
    scale[c] = sc;
    shift[c] = be[c] - mean * sc;
}

// ---------------------------------------------------------------------------
// Final BN apply + ReLU (in place on d_out).
// ---------------------------------------------------------------------------
__global__ __launch_bounds__(256) void bn_apply_relu_kernel(
    float* __restrict__ h, const float* __restrict__ scale,
    const float* __restrict__ shift, int n4)
{
    int i = blockIdx.x * 256 + threadIdx.x;
    if (i >= n4) return;
    int cb = i & 31;
    float4 v  = ((float4*)h)[i];
    float4 sc = ((const float4*)scale)[cb];
    float4 sh = ((const float4*)shift)[cb];
    v.x = fmaxf(fmaf(v.x, sc.x, sh.x), 0.f);
    v.y = fmaxf(fmaf(v.y, sc.y, sh.y), 0.f);
    v.z = fmaxf(fmaf(v.z, sc.z, sh.z), 0.f);
    v.w = fmaxf(fmaf(v.w, sc.w, sh.w), 0.f);
    ((float4*)h)[i] = v;
}

extern "C" void kernel_launch(void* const* d_in, const int* in_sizes, int n_in,
                              void* d_out, int out_size, void* d_ws, size_t ws_size,
                              hipStream_t stream) {
    const float* x   = (const float*)d_in[0];
    const int*   ei  = (const int*)d_in[1];
    const float* W1l = (const float*)d_in[2];
    const float* b1  = (const float*)d_in[3];
    const float* W1r = (const float*)d_in[4];
    const float* g1  = (const float*)d_in[5];
    const float* be1 = (const float*)d_in[6];
    const float* W2l = (const float*)d_in[7];
    const float* b2  = (const float*)d_in[8];
    const float* W2r = (const float*)d_in[9];
    const float* g2  = (const float*)d_in[10];
    const float* be2 = (const float*)d_in[11];
    float* out = (float*)d_out;

    const int N = N_NODES, E = N_EDGES;

    // Workspace layout (floats):
    // [0..1024)        stats: gsum1,gsq1,gsum2,gsq2,scale1,shift1,scale2,shift2
    // [1024..25600)    packed bf16 weights: W1lp(4096f) W1rp(4096f) W2lp(8192f) W2rp(8192f)
    // [25600.. +N*128) R1: agg1 (N*64 used) then agg2 (N*128)
    // t1 (raw relu(sage1) output) lives in d_out; gemm2 overwrites it in place
    // (row-local: each wave reads its rows' X before the epilogue store).
    float* ws     = (float*)d_ws;
    float* gsum1  = ws;        float* gsq1   = ws + 128;
    float* gsum2  = ws + 256;  float* gsq2   = ws + 384;
    float* scale1 = ws + 512;  float* shift1 = ws + 640;
    float* scale2 = ws + 768;  float* shift2 = ws + 896;
    short* W1lp = (short*)(ws + 1024);
    short* W1rp = (short*)(ws + 1024 + 4096);
    short* W2lp = (short*)(ws + 1024 + 8192);
    short* W2rp = (short*)(ws + 1024 + 16384);
    float* R1 = ws + 25600;
    float* t1 = out;

    // ---- Prep ----
    hipMemsetAsync(ws, 0, 1024 * sizeof(float), stream);                 // stats
    hipMemsetAsync(R1, 0, (size_t)N * F_IN * sizeof(float), stream);     // agg1
    pack_weights_kernel<<<4, 256, 0, stream>>>(W1l, W1lp, 2);
    pack_weights_kernel<<<4, 256, 0, stream>>>(W1r, W1rp, 2);
    pack_weights_kernel<<<8, 256, 0, stream>>>(W2l, W2lp, 4);
    pack_weights_kernel<<<8, 256, 0, stream>>>(W2r, W2rp, 4);

    // ---- Layer 1 ----
    scatter_add_kernel<<<(E * F_IN + 255) / 256, 256, 0, stream>>>(x, ei, R1, E);
    gemm_mfma_kernel<F_IN, false><<<N / 64, 256, 0, stream>>>(
        R1, x, W1lp, W1rp, b1, nullptr, nullptr, t1, gsum1, gsq1);
    bn_finalize_kernel<<<1, 128, 0, stream>>>(gsum1, gsq1, g1, be1, scale1, shift1, 1.f / N);

    // ---- Layer 2 ----
    hipMemsetAsync(R1, 0, (size_t)N * F_H * sizeof(float), stream);      // agg2
    scatter_add_bn_kernel<<<(E * F_H + 255) / 256, 256, 0, stream>>>(
        t1, ei, scale1, shift1, R1, E);
    gemm_mfma_kernel<F_H, true><<<N / 64, 256, 0, stream>>>(
        R1, t1, W2lp, W2rp, b2, scale1, shift1, out, gsum2, gsq2);
    bn_finalize_kernel<<<1, 128, 0, stream>>>(gsum2, gsq2, g2, be2, scale2, shift2, 1.f / N);
    bn_apply_relu_kernel<<<(N * F_H / 4 + 255) / 256, 256, 0, stream>>>(
        out, scale2, shift2, N * F_H / 4);
}

// Round 3
// 882.240 us; speedup vs baseline: 2.6609x; 1.4043x over previous
//
#include <hip/hip_runtime.h>

#define N_NODES 200000
#define N_EDGES 1200000
#define F_IN    64
#define F_H     128
#define BN_EPS  1e-5f

typedef short bf16x8 __attribute__((ext_vector_type(8)));   // 8 bf16 in 4 VGPRs
typedef float f32x4  __attribute__((ext_vector_type(4)));

__device__ __forceinline__ unsigned short f2bf(float f) {
    union { float f; unsigned u; } v; v.f = f;
    unsigned r = (v.u + 0x7FFFu + ((v.u >> 16) & 1u)) >> 16;  // RNE
    return (unsigned short)r;
}
__device__ __forceinline__ float bf2f(unsigned short b) {
    union { unsigned u; float f; } v; v.u = ((unsigned)b) << 16;
    return v.f;
}

// ---------------------------------------------------------------------------
// Weight pack into bf16 MFMA B-fragment order for mfma_f32_16x16x32_bf16:
// element j of lane L in (nt,kt) tile = W[kt*32+(L>>4)*8+j][nt*16+(L&15)],
// optionally pre-scaled per-k (folds BN1 scale into layer-2 weights).
// ---------------------------------------------------------------------------
__global__ void pack_weights_kernel(const float* __restrict__ W,
                                    const float* __restrict__ kscale,
                                    short* __restrict__ P, int KT)
{
    int t = blockIdx.x * 256 + threadIdx.x;            // over 8*KT*64
    if (t >= 8 * KT * 64) return;
    int lane = t & 63;
    int kt   = (t >> 6) % KT;
    int nt   = t / (64 * KT);
    int k0   = kt * 32 + (lane >> 4) * 8;
    int n    = nt * 16 + (lane & 15);
#pragma unroll
    for (int j = 0; j < 8; ++j) {
        float w = W[(size_t)(k0 + j) * 128 + n];
        if (kscale) w *= kscale[k0 + j];
        P[(size_t)t * 8 + j] = (short)f2bf(w);
    }
}

// ---------------------------------------------------------------------------
// CSR build: histogram -> 2-level exclusive scan -> cursor fill
// ---------------------------------------------------------------------------
__global__ __launch_bounds__(256) void hist_kernel(const int* __restrict__ ei,
                                                   int* __restrict__ deg, int E)
{
    int e = blockIdx.x * 256 + threadIdx.x;
    if (e < E) atomicAdd(&deg[ei[E + e]], 1);
}

// 1024 items per block (256 thr x 4). part[] = exclusive prefix within block.
__global__ __launch_bounds__(256) void scan1_kernel(const int* __restrict__ deg,
        int* __restrict__ part, int* __restrict__ bsum, int n)
{
    __shared__ int s[256];
    int t = threadIdx.x;
    int base = blockIdx.x * 1024 + t * 4;
    int v[4];
#pragma unroll
    for (int j = 0; j < 4; ++j) v[j] = (base + j < n) ? deg[base + j] : 0;
    int tsum = v[0] + v[1] + v[2] + v[3];
    s[t] = tsum;
    __syncthreads();
    for (int off = 1; off < 256; off <<= 1) {
        int xv = (t >= off) ? s[t - off] : 0;
        __syncthreads();
        s[t] += xv;
        __syncthreads();
    }
    int excl = s[t] - tsum;
#pragma unroll
    for (int j = 0; j < 4; ++j) {
        if (base + j < n) part[base + j] = excl;
        excl += v[j];
    }
    if (t == 255) bsum[blockIdx.x] = s[255];
}

__global__ void scan2_kernel(int* __restrict__ bsum, int nb)
{
    __shared__ int s[256];
    int t = threadIdx.x;
    int v = (t < nb) ? bsum[t] : 0;
    s[t] = v;
    __syncthreads();
    for (int off = 1; off < 256; off <<= 1) {
        int xv = (t >= off) ? s[t - off] : 0;
        __syncthreads();
        s[t] += xv;
        __syncthreads();
    }
    if (t < nb) bsum[t] = s[t] - v;   // exclusive
}

__global__ __launch_bounds__(256) void scan3_kernel(
    const int* __restrict__ part, const int* __restrict__ bsum,
    const int* __restrict__ deg, int* __restrict__ rowptr,
    int* __restrict__ cursor, float* __restrict__ degf, int n, int E)
{
    int i = blockIdx.x * 256 + threadIdx.x;
    if (i == 0) rowptr[n] = E;
    if (i >= n) return;
    int r = part[i] + bsum[i >> 10];
    rowptr[i] = r;
    cursor[i] = r;
    degf[i]   = (float)deg[i];
}

__global__ __launch_bounds__(256) void fill_kernel(const int* __restrict__ ei,
        int* __restrict__ cursor, int* __restrict__ ssrc, int E)
{
    int e = blockIdx.x * 256 + threadIdx.x;
    if (e >= E) return;
    int d = ei[E + e];
    int pos = atomicAdd(&cursor[d], 1);
    ssrc[pos] = ei[e];
}

// ---------------------------------------------------------------------------
// Gather-aggregate layer 1: agg[row,0:64] = sum over neighbors of x[src,:].
// One wave per row (64 lanes = 64 cols); no divergence, no atomics.
// ---------------------------------------------------------------------------
__global__ __launch_bounds__(256) void gather1_kernel(
    const float* __restrict__ x, const int* __restrict__ rowptr,
    const int* __restrict__ ssrc, float* __restrict__ agg)
{
    int row = blockIdx.x * 4 + (threadIdx.x >> 6);
    int col = threadIdx.x & 63;
    int b = rowptr[row], e = rowptr[row + 1];
    float acc = 0.f;
    for (int j = b; j < e; ++j) {
        int s = ssrc[j];
        acc += x[(size_t)s * F_IN + col];
    }
    agg[(size_t)row * F_IN + col] = acc;
}

// ---------------------------------------------------------------------------
// Gather-aggregate layer 2: agg[row,0:128] = sum of raw bf16 t1[src,:].
// One wave per row, each lane covers 2 cols (ushort2 load -> float2 acc).
// ---------------------------------------------------------------------------
__global__ __launch_bounds__(256) void gather2_kernel(
    const unsigned short* __restrict__ t1, const int* __restrict__ rowptr,
    const int* __restrict__ ssrc, float* __restrict__ agg)
{
    int row = blockIdx.x * 4 + (threadIdx.x >> 6);
    int l   = threadIdx.x & 63;
    int b = rowptr[row], e = rowptr[row + 1];
    float2 acc = {0.f, 0.f};
    for (int j = b; j < e; ++j) {
        int s = ssrc[j];
        unsigned u = *(const unsigned*)(t1 + (size_t)s * F_H + l * 2);
        union { unsigned u; float f; } lo, hi;
        lo.u = u << 16;
        hi.u = u & 0xFFFF0000u;
        acc.x += lo.f;
        acc.y += hi.f;
    }
    ((float2*)(agg + (size_t)row * F_H))[l] = acc;
}

// ---------------------------------------------------------------------------
// MFMA GEMM, 128 output cols, bf16 16x16x32. Wave = 16 rows; 8 n-tiles.
// L1: out = relu(A@W1l + b1 + X@W1r), X fp32, output bf16 -> t1, stats.
// L2: out = relu(A@W2l' + Xb@W2r' + crb + deg*c2), Xb bf16 t1, output fp32, stats.
//     (scale1 folded into W2l'/W2r'; crb = shift1@W2r + b2; c2 = shift1@W2l)
// ---------------------------------------------------------------------------
template<int K, bool L2>
__global__ __launch_bounds__(256) void gemm_mfma_kernel(
    const float* __restrict__ A,
    const float* __restrict__ Xf,
    const unsigned short* __restrict__ Xb,
    const short* __restrict__ Wlp, const short* __restrict__ Wrp,
    const float* __restrict__ bias,
    const float* __restrict__ c2, const float* __restrict__ degf,
    float* __restrict__ outF, unsigned short* __restrict__ outB,
    float* __restrict__ gsum, float* __restrict__ gsq)
{
    constexpr int KT = K / 32;
    __shared__ float sS[128];
    __shared__ float sQ[128];

    const int tid  = threadIdx.x;
    const int lane = tid & 63;
    const int wv   = tid >> 6;
    const int m    = lane & 15;
    const int quad = lane >> 4;
    const int rowbase = blockIdx.x * 64 + wv * 16;
    const int row  = rowbase + m;

    if (tid < 128) { sS[tid] = 0.f; sQ[tid] = 0.f; }

    f32x4 acc[8] = {};

#pragma unroll
    for (int kt = 0; kt < KT; ++kt) {
        const int k0 = kt * 32 + quad * 8;
        const float4* ap = (const float4*)(A + (size_t)row * K + k0);
        float4 a0 = ap[0], a1 = ap[1];
        bf16x8 af, xf;
        af[0] = (short)f2bf(a0.x); af[1] = (short)f2bf(a0.y);
        af[2] = (short)f2bf(a0.z); af[3] = (short)f2bf(a0.w);
        af[4] = (short)f2bf(a1.x); af[5] = (short)f2bf(a1.y);
        af[6] = (short)f2bf(a1.z); af[7] = (short)f2bf(a1.w);
        if constexpr (L2) {
            xf = *(const bf16x8*)(Xb + (size_t)row * K + k0);
        } else {
            const float4* xp = (const float4*)(Xf + (size_t)row * K + k0);
            float4 x0 = xp[0], x1 = xp[1];
            xf[0] = (short)f2bf(x0.x); xf[1] = (short)f2bf(x0.y);
            xf[2] = (short)f2bf(x0.z); xf[3] = (short)f2bf(x0.w);
            xf[4] = (short)f2bf(x1.x); xf[5] = (short)f2bf(x1.y);
            xf[6] = (short)f2bf(x1.z); xf[7] = (short)f2bf(x1.w);
        }

#pragma unroll
        for (int nt = 0; nt < 8; ++nt) {
            bf16x8 wl = *(const bf16x8*)(Wlp + ((size_t)(nt * KT + kt) * 64 + lane) * 8);
            acc[nt] = __builtin_amdgcn_mfma_f32_16x16x32_bf16(af, wl, acc[nt], 0, 0, 0);
            bf16x8 wr = *(const bf16x8*)(Wrp + ((size_t)(nt * KT + kt) * 64 + lane) * 8);
            acc[nt] = __builtin_amdgcn_mfma_f32_16x16x32_bf16(xf, wr, acc[nt], 0, 0, 0);
        }
    }

    __syncthreads();   // sS/sQ init done

    // C/D layout: col = lane&15, row = quad*4 + reg
    const int col_l = lane & 15;
    const int orow  = rowbase + quad * 4;
    float dg[4];
    if constexpr (L2) {
#pragma unroll
        for (int r = 0; r < 4; ++r) dg[r] = degf[orow + r];
    }
#pragma unroll
    for (int nt = 0; nt < 8; ++nt) {
        int col = nt * 16 + col_l;
        float b = bias[col];
        float cc = L2 ? c2[col] : 0.f;
        float s = 0.f, q = 0.f;
#pragma unroll
        for (int r = 0; r < 4; ++r) {
            float base = L2 ? fmaf(dg[r], cc, b) : b;
            float v = fmaxf(acc[nt][r] + base, 0.f);
            if constexpr (L2) outF[(size_t)(orow + r) * 128 + col] = v;
            else              outB[(size_t)(orow + r) * 128 + col] = f2bf(v);
            s += v;
            q = fmaf(v, v, q);
        }
        atomicAdd(&sS[col], s);
        atomicAdd(&sQ[col], q);
    }
    __syncthreads();
    if (tid < 128) {
        atomicAdd(&gsum[tid], sS[tid]);
        atomicAdd(&gsq[tid],  sQ[tid]);
    }
}

// ---------------------------------------------------------------------------
// BN finalize: per-feature scale/shift.
// ---------------------------------------------------------------------------
__global__ void bn_finalize_kernel(
    const float* __restrict__ gsum, const float* __restrict__ gsq,
    const float* __restrict__ g, const float* __restrict__ be,
    float* __restrict__ scale, float* __restrict__ shift, float invN)
{
    int c = threadIdx.x;  // 128
    float mean = gsum[c] * invN;
    float var  = fmaxf(gsq[c] * invN - mean * mean, 0.f);
    float sc   = g[c] * rsqrtf(var + BN_EPS);
    scale[c] = sc;
    shift[c] = be[c] - mean * sc;
}

// BN1 fold constants: c2 = shift1@W2l ; crb = shift1@W2r + b2
__global__ void bn_fold_kernel(
    const float* __restrict__ shift1, const float* __restrict__ W2l,
    const float* __restrict__ W2r, const float* __restrict__ b2,
    float* __restrict__ c2, float* __restrict__ crb)
{
    int col = threadIdx.x;  // 128
    float a = 0.f, r = 0.f;
    for (int k = 0; k < 128; ++k) {
        float s = shift1[k];
        a = fmaf(s, W2l[(size_t)k * 128 + col], a);
        r = fmaf(s, W2r[(size_t)k * 128 + col], r);
    }
    c2[col]  = a;
    crb[col] = r + b2[col];
}

// ---------------------------------------------------------------------------
// Final BN apply + ReLU (in place on d_out).
// ---------------------------------------------------------------------------
__global__ __launch_bounds__(256) void bn_apply_relu_kernel(
    float* __restrict__ h, const float* __restrict__ scale,
    const float* __restrict__ shift, int n4)
{
    int i = blockIdx.x * 256 + threadIdx.x;
    if (i >= n4) return;
    int cb = i & 31;
    float4 v  = ((float4*)h)[i];
    float4 sc = ((const float4*)scale)[cb];
    float4 sh = ((const float4*)shift)[cb];
    v.x = fmaxf(fmaf(v.x, sc.x, sh.x), 0.f);
    v.y = fmaxf(fmaf(v.y, sc.y, sh.y), 0.f);
    v.z = fmaxf(fmaf(v.z, sc.z, sh.z), 0.f);
    v.w = fmaxf(fmaf(v.w, sc.w, sh.w), 0.f);
    ((float4*)h)[i] = v;
}

extern "C" void kernel_launch(void* const* d_in, const int* in_sizes, int n_in,
                              void* d_out, int out_size, void* d_ws, size_t ws_size,
                              hipStream_t stream) {
    const float* x   = (const float*)d_in[0];
    const int*   ei  = (const int*)d_in[1];
    const float* W1l = (const float*)d_in[2];
    const float* b1  = (const float*)d_in[3];
    const float* W1r = (const float*)d_in[4];
    const float* g1  = (const float*)d_in[5];
    const float* be1 = (const float*)d_in[6];
    const float* W2l = (const float*)d_in[7];
    const float* b2  = (const float*)d_in[8];
    const float* W2r = (const float*)d_in[9];
    const float* g2  = (const float*)d_in[10];
    const float* be2 = (const float*)d_in[11];
    float* out = (float*)d_out;

    const int N = N_NODES, E = N_EDGES;
    const int NB1 = (N + 1023) / 1024;          // 196 scan blocks

    // Workspace layout (float units):
    float* ws     = (float*)d_ws;
    float* gsum1  = ws;        float* gsq1   = ws + 128;
    float* gsum2  = ws + 256;  float* gsq2   = ws + 384;
    float* scale1 = ws + 512;  float* shift1 = ws + 640;
    float* scale2 = ws + 768;  float* shift2 = ws + 896;
    float* c2v    = ws + 1024; float* crb    = ws + 1152;     // fold constants
    short* W1lp = (short*)(ws + 1536);                        // 4096 f
    short* W1rp = (short*)(ws + 1536 + 4096);                 // 4096 f
    short* W2lp = (short*)(ws + 1536 + 8192);                 // 8192 f
    short* W2rp = (short*)(ws + 1536 + 16384);                // 8192 f
    int*   deg    = (int*)(ws + 26112);                       // N
    int*   part   = deg + N;                                  // N
    int*   bsum   = part + N;                                 // 1024
    int*   rowptr = bsum + 1024;                              // N+1
    int*   cursor = rowptr + (N + 1024);                      // N (padded)
    float* degf   = (float*)(cursor + N);                     // N
    int*   ssrc   = (int*)(degf + N);                         // E
    unsigned short* t1 = (unsigned short*)(ssrc + E);         // N*128 bf16
    float* agg    = (float*)(t1 + (size_t)N * F_H);           // N*128 fp32

    // ---- Graph build + layer-1 weight pack ----
    hipMemsetAsync(ws, 0, 1024 * sizeof(float), stream);      // stats
    hipMemsetAsync(deg, 0, (size_t)N * sizeof(int), stream);
    pack_weights_kernel<<<4, 256, 0, stream>>>(W1l, nullptr, W1lp, 2);
    pack_weights_kernel<<<4, 256, 0, stream>>>(W1r, nullptr, W1rp, 2);
    hist_kernel<<<(E + 255) / 256, 256, 0, stream>>>(ei, deg, E);
    scan1_kernel<<<NB1, 256, 0, stream>>>(deg, part, bsum, N);
    scan2_kernel<<<1, 256, 0, stream>>>(bsum, NB1);
    scan3_kernel<<<(N + 255) / 256, 256, 0, stream>>>(part, bsum, deg, rowptr,
                                                      cursor, degf, N, E);
    fill_kernel<<<(E + 255) / 256, 256, 0, stream>>>(ei, cursor, ssrc, E);

    // ---- Layer 1 ----
    gather1_kernel<<<N / 4, 256, 0, stream>>>(x, rowptr, ssrc, agg);
    gemm_mfma_kernel<F_IN, false><<<N / 64, 256, 0, stream>>>(
        agg, x, nullptr, W1lp, W1rp, b1, nullptr, nullptr,
        nullptr, t1, gsum1, gsq1);
    bn_finalize_kernel<<<1, 128, 0, stream>>>(gsum1, gsq1, g1, be1,
                                              scale1, shift1, 1.f / N);

    // ---- Layer 2 (BN1 folded: scale1 into weights, shift1 into c2/crb) ----
    pack_weights_kernel<<<8, 256, 0, stream>>>(W2l, scale1, W2lp, 4);
    pack_weights_kernel<<<8, 256, 0, stream>>>(W2r, scale1, W2rp, 4);
    bn_fold_kernel<<<1, 128, 0, stream>>>(shift1, W2l, W2r, b2, c2v, crb);
    gather2_kernel<<<N / 4, 256, 0, stream>>>(t1, rowptr, ssrc, agg);
    gemm_mfma_kernel<F_H, true><<<N / 64, 256, 0, stream>>>(
        agg, nullptr, t1, W2lp, W2rp, crb, c2v, degf,
        out, nullptr, gsum2, gsq2);
    bn_finalize_kernel<<<1, 128, 0, stream>>>(gsum2, gsq2, g2, be2,
                                              scale2, shift2, 1.f / N);
    bn_apply_relu_kernel<<<(N * F_H / 4 + 255) / 256, 256, 0, stream>>>(
        out, scale2, shift2, N * F_H / 4);
}

// Round 4
// 698.211 us; speedup vs baseline: 3.3623x; 1.2636x over previous
//
#include <hip/hip_runtime.h>

#define N_NODES 200000
#define N_EDGES 1200000
#define F_IN    64
#define F_H     128
#define BN_EPS  1e-5f

typedef short bf16x8 __attribute__((ext_vector_type(8)));   // 8 bf16 in 4 VGPRs
typedef float f32x4  __attribute__((ext_vector_type(4)));
typedef unsigned short us4 __attribute__((ext_vector_type(4)));

__device__ __forceinline__ unsigned short f2bf(float f) {
    union { float f; unsigned u; } v; v.f = f;
    unsigned r = (v.u + 0x7FFFu + ((v.u >> 16) & 1u)) >> 16;  // RNE
    return (unsigned short)r;
}
__device__ __forceinline__ float bf2f(unsigned short b) {
    union { unsigned u; float f; } v; v.u = ((unsigned)b) << 16;
    return v.f;
}

// ---------------------------------------------------------------------------
// Weight pack into bf16 MFMA B-fragment order for mfma_f32_16x16x32_bf16:
// element j of lane L in (nt,kt) tile = W[kt*32+(L>>4)*8+j][nt*16+(L&15)],
// optionally pre-scaled per-k (folds BN1 scale into layer-2 weights).
// ---------------------------------------------------------------------------
__global__ void pack_weights_kernel(const float* __restrict__ W,
                                    const float* __restrict__ kscale,
                                    short* __restrict__ P, int KT)
{
    int t = blockIdx.x * 256 + threadIdx.x;            // over 8*KT*64
    if (t >= 8 * KT * 64) return;
    int lane = t & 63;
    int kt   = (t >> 6) % KT;
    int nt   = t / (64 * KT);
    int k0   = kt * 32 + (lane >> 4) * 8;
    int n    = nt * 16 + (lane & 15);
#pragma unroll
    for (int j = 0; j < 8; ++j) {
        float w = W[(size_t)(k0 + j) * 128 + n];
        if (kscale) w *= kscale[k0 + j];
        P[(size_t)t * 8 + j] = (short)f2bf(w);
    }
}

// ---------------------------------------------------------------------------
// CSR build: histogram -> 2-level exclusive scan -> cursor fill
// ---------------------------------------------------------------------------
__global__ __launch_bounds__(256) void hist_kernel(const int* __restrict__ ei,
                                                   int* __restrict__ deg, int E)
{
    int e = blockIdx.x * 256 + threadIdx.x;
    if (e < E) atomicAdd(&deg[ei[E + e]], 1);
}

__global__ __launch_bounds__(256) void scan1_kernel(const int* __restrict__ deg,
        int* __restrict__ part, int* __restrict__ bsum, int n)
{
    __shared__ int s[256];
    int t = threadIdx.x;
    int base = blockIdx.x * 1024 + t * 4;
    int v[4];
#pragma unroll
    for (int j = 0; j < 4; ++j) v[j] = (base + j < n) ? deg[base + j] : 0;
    int tsum = v[0] + v[1] + v[2] + v[3];
    s[t] = tsum;
    __syncthreads();
    for (int off = 1; off < 256; off <<= 1) {
        int xv = (t >= off) ? s[t - off] : 0;
        __syncthreads();
        s[t] += xv;
        __syncthreads();
    }
    int excl = s[t] - tsum;
#pragma unroll
    for (int j = 0; j < 4; ++j) {
        if (base + j < n) part[base + j] = excl;
        excl += v[j];
    }
    if (t == 255) bsum[blockIdx.x] = s[255];
}

__global__ void scan2_kernel(int* __restrict__ bsum, int nb)
{
    __shared__ int s[256];
    int t = threadIdx.x;
    int v = (t < nb) ? bsum[t] : 0;
    s[t] = v;
    __syncthreads();
    for (int off = 1; off < 256; off <<= 1) {
        int xv = (t >= off) ? s[t - off] : 0;
        __syncthreads();
        s[t] += xv;
        __syncthreads();
    }
    if (t < nb) bsum[t] = s[t] - v;   // exclusive
}

__global__ __launch_bounds__(256) void scan3_kernel(
    const int* __restrict__ part, const int* __restrict__ bsum,
    const int* __restrict__ deg, int* __restrict__ rowptr,
    int* __restrict__ cursor, float* __restrict__ degf, int n, int E)
{
    int i = blockIdx.x * 256 + threadIdx.x;
    if (i == 0) rowptr[n] = E;
    if (i >= n) return;
    int r = part[i] + bsum[i >> 10];
    rowptr[i] = r;
    cursor[i] = r;
    degf[i]   = (float)deg[i];
}

__global__ __launch_bounds__(256) void fill_kernel(const int* __restrict__ ei,
        int* __restrict__ cursor, int* __restrict__ ssrc, int E)
{
    int e = blockIdx.x * 256 + threadIdx.x;
    if (e >= E) return;
    int d = ei[E + e];
    int pos = atomicAdd(&cursor[d], 1);
    ssrc[pos] = ei[e];
}

// ---------------------------------------------------------------------------
// Gather-aggregate layer 1: aggb[row,0:64] = bf16( sum_src x[src,:] ).
// 4 rows per wave: sub = lane>>4 selects row, li = lane&15 covers cols as
// float4. Four independent neighbor chains per wave + software-pipelined
// ssrc prefetch breaks the dependent-load latency chain.
// ---------------------------------------------------------------------------
__global__ __launch_bounds__(256) void gather1_kernel(
    const float* __restrict__ x, const int* __restrict__ rowptr,
    const int* __restrict__ ssrc, unsigned short* __restrict__ aggb)
{
    const int tid  = threadIdx.x;
    const int wv   = tid >> 6;
    const int lane = tid & 63;
    const int sub  = lane >> 4;
    const int li   = lane & 15;
    const int row  = blockIdx.x * 16 + wv * 4 + sub;

    int b = rowptr[row], e = rowptr[row + 1];
    float4 acc = {0.f, 0.f, 0.f, 0.f};
    if (b < e) {
        int s = ssrc[b];
        for (int j = b; j < e; ++j) {
            int sn = (j + 1 < e) ? ssrc[j + 1] : 0;   // prefetch next index
            float4 v = ((const float4*)(x + (size_t)s * F_IN))[li];
            acc.x += v.x; acc.y += v.y; acc.z += v.z; acc.w += v.w;
            s = sn;
        }
    }
    us4 o;
    o.x = f2bf(acc.x); o.y = f2bf(acc.y); o.z = f2bf(acc.z); o.w = f2bf(acc.w);
    *(us4*)(aggb + (size_t)row * F_IN + li * 4) = o;
}

// ---------------------------------------------------------------------------
// Gather-aggregate layer 2: aggb[row,0:128] = bf16( sum_src t1[src,:] ),
// t1 bf16. Same 4-rows-per-wave + prefetch structure; li covers 8 cols.
// ---------------------------------------------------------------------------
__global__ __launch_bounds__(256) void gather2_kernel(
    const unsigned short* __restrict__ t1, const int* __restrict__ rowptr,
    const int* __restrict__ ssrc, unsigned short* __restrict__ aggb)
{
    const int tid  = threadIdx.x;
    const int wv   = tid >> 6;
    const int lane = tid & 63;
    const int sub  = lane >> 4;
    const int li   = lane & 15;
    const int row  = blockIdx.x * 16 + wv * 4 + sub;

    int b = rowptr[row], e = rowptr[row + 1];
    float acc[8] = {};
    if (b < e) {
        int s = ssrc[b];
        for (int j = b; j < e; ++j) {
            int sn = (j + 1 < e) ? ssrc[j + 1] : 0;
            bf16x8 v = *(const bf16x8*)(t1 + (size_t)s * F_H + li * 8);
#pragma unroll
            for (int k = 0; k < 8; ++k) acc[k] += bf2f((unsigned short)v[k]);
            s = sn;
        }
    }
    bf16x8 o;
#pragma unroll
    for (int k = 0; k < 8; ++k) o[k] = (short)f2bf(acc[k]);
    *(bf16x8*)(aggb + (size_t)row * F_H + li * 8) = o;
}

// ---------------------------------------------------------------------------
// MFMA GEMM, 128 output cols, bf16 16x16x32. Wave = 16 rows; 8 n-tiles.
// A operand is bf16 (packed row-major), loaded directly as bf16x8 fragments.
// L1: out = relu(A@W1l + b1 + X@W1r), X fp32 -> t1 bf16, stats.
// L2: out = relu(A@W2l' + Xb@W2r' + crb + deg*c2), Xb bf16, out fp32, stats.
// ---------------------------------------------------------------------------
template<int K, bool L2>
__global__ __launch_bounds__(256) void gemm_mfma_kernel(
    const unsigned short* __restrict__ Ab,
    const float* __restrict__ Xf,
    const unsigned short* __restrict__ Xb,
    const short* __restrict__ Wlp, const short* __restrict__ Wrp,
    const float* __restrict__ bias,
    const float* __restrict__ c2, const float* __restrict__ degf,
    float* __restrict__ outF, unsigned short* __restrict__ outB,
    float* __restrict__ gsum, float* __restrict__ gsq)
{
    constexpr int KT = K / 32;
    __shared__ float sS[128];
    __shared__ float sQ[128];

    const int tid  = threadIdx.x;
    const int lane = tid & 63;
    const int wv   = tid >> 6;
    const int m    = lane & 15;
    const int quad = lane >> 4;
    const int rowbase = blockIdx.x * 64 + wv * 16;
    const int row  = rowbase + m;

    if (tid < 128) { sS[tid] = 0.f; sQ[tid] = 0.f; }

    f32x4 acc[8] = {};

#pragma unroll
    for (int kt = 0; kt < KT; ++kt) {
        const int k0 = kt * 32 + quad * 8;
        bf16x8 af = *(const bf16x8*)(Ab + (size_t)row * K + k0);
        bf16x8 xf;
        if constexpr (L2) {
            xf = *(const bf16x8*)(Xb + (size_t)row * K + k0);
        } else {
            const float4* xp = (const float4*)(Xf + (size_t)row * K + k0);
            float4 x0 = xp[0], x1 = xp[1];
            xf[0] = (short)f2bf(x0.x); xf[1] = (short)f2bf(x0.y);
            xf[2] = (short)f2bf(x0.z); xf[3] = (short)f2bf(x0.w);
            xf[4] = (short)f2bf(x1.x); xf[5] = (short)f2bf(x1.y);
            xf[6] = (short)f2bf(x1.z); xf[7] = (short)f2bf(x1.w);
        }

#pragma unroll
        for (int nt = 0; nt < 8; ++nt) {
            bf16x8 wl = *(const bf16x8*)(Wlp + ((size_t)(nt * KT + kt) * 64 + lane) * 8);
            acc[nt] = __builtin_amdgcn_mfma_f32_16x16x32_bf16(af, wl, acc[nt], 0, 0, 0);
            bf16x8 wr = *(const bf16x8*)(Wrp + ((size_t)(nt * KT + kt) * 64 + lane) * 8);
            acc[nt] = __builtin_amdgcn_mfma_f32_16x16x32_bf16(xf, wr, acc[nt], 0, 0, 0);
        }
    }

    __syncthreads();   // sS/sQ init done

    // C/D layout: col = lane&15, row = quad*4 + reg
    const int col_l = lane & 15;
    const int orow  = rowbase + quad * 4;
    float dg[4];
    if constexpr (L2) {
#pragma unroll
        for (int r = 0; r < 4; ++r) dg[r] = degf[orow + r];
    }
#pragma unroll
    for (int nt = 0; nt < 8; ++nt) {
        int col = nt * 16 + col_l;
        float b = bias[col];
        float cc = L2 ? c2[col] : 0.f;
        float s = 0.f, q = 0.f;
#pragma unroll
        for (int r = 0; r < 4; ++r) {
            float base = L2 ? fmaf(dg[r], cc, b) : b;
            float v = fmaxf(acc[nt][r] + base, 0.f);
            if constexpr (L2) outF[(size_t)(orow + r) * 128 + col] = v;
            else              outB[(size_t)(orow + r) * 128 + col] = f2bf(v);
            s += v;
            q = fmaf(v, v, q);
        }
        atomicAdd(&sS[col], s);
        atomicAdd(&sQ[col], q);
    }
    __syncthreads();
    if (tid < 128) {
        atomicAdd(&gsum[tid], sS[tid]);
        atomicAdd(&gsq[tid],  sQ[tid]);
    }
}

// ---------------------------------------------------------------------------
// BN finalize: per-feature scale/shift.
// ---------------------------------------------------------------------------
__global__ void bn_finalize_kernel(
    const float* __restrict__ gsum, const float* __restrict__ gsq,
    const float* __restrict__ g, const float* __restrict__ be,
    float* __restrict__ scale, float* __restrict__ shift, float invN)
{
    int c = threadIdx.x;  // 128
    float mean = gsum[c] * invN;
    float var  = fmaxf(gsq[c] * invN - mean * mean, 0.f);
    float sc   = g[c] * rsqrtf(var + BN_EPS);
    scale[c] = sc;
    shift[c] = be[c] - mean * sc;
}

// BN1 fold constants: c2 = shift1@W2l ; crb = shift1@W2r + b2
__global__ void bn_fold_kernel(
    const float* __restrict__ shift1, const float* __restrict__ W2l,
    const float* __restrict__ W2r, const float* __restrict__ b2,
    float* __restrict__ c2, float* __restrict__ crb)
{
    int col = threadIdx.x;  // 128
    float a = 0.f, r = 0.f;
    for (int k = 0; k < 128; ++k) {
        float s = shift1[k];
        a = fmaf(s, W2l[(size_t)k * 128 + col], a);
        r = fmaf(s, W2r[(size_t)k * 128 + col], r);
    }
    c2[col]  = a;
    crb[col] = r + b2[col];
}

// ---------------------------------------------------------------------------
// Final BN apply + ReLU (in place on d_out).
// ---------------------------------------------------------------------------
__global__ __launch_bounds__(256) void bn_apply_relu_kernel(
    float* __restrict__ h, const float* __restrict__ scale,
    const float* __restrict__ shift, int n4)
{
    int i = blockIdx.x * 256 + threadIdx.x;
    if (i >= n4) return;
    int cb = i & 31;
    float4 v  = ((float4*)h)[i];
    float4 sc = ((const float4*)scale)[cb];
    float4 sh = ((const float4*)shift)[cb];
    v.x = fmaxf(fmaf(v.x, sc.x, sh.x), 0.f);
    v.y = fmaxf(fmaf(v.y, sc.y, sh.y), 0.f);
    v.z = fmaxf(fmaf(v.z, sc.z, sh.z), 0.f);
    v.w = fmaxf(fmaf(v.w, sc.w, sh.w), 0.f);
    ((float4*)h)[i] = v;
}

extern "C" void kernel_launch(void* const* d_in, const int* in_sizes, int n_in,
                              void* d_out, int out_size, void* d_ws, size_t ws_size,
                              hipStream_t stream) {
    const float* x   = (const float*)d_in[0];
    const int*   ei  = (const int*)d_in[1];
    const float* W1l = (const float*)d_in[2];
    const float* b1  = (const float*)d_in[3];
    const float* W1r = (const float*)d_in[4];
    const float* g1  = (const float*)d_in[5];
    const float* be1 = (const float*)d_in[6];
    const float* W2l = (const float*)d_in[7];
    const float* b2  = (const float*)d_in[8];
    const float* W2r = (const float*)d_in[9];
    const float* g2  = (const float*)d_in[10];
    const float* be2 = (const float*)d_in[11];
    float* out = (float*)d_out;

    const int N = N_NODES, E = N_EDGES;
    const int NB1 = (N + 1023) / 1024;          // 196 scan blocks

    // Workspace layout (float units):
    float* ws     = (float*)d_ws;
    float* gsum1  = ws;        float* gsq1   = ws + 128;
    float* gsum2  = ws + 256;  float* gsq2   = ws + 384;
    float* scale1 = ws + 512;  float* shift1 = ws + 640;
    float* scale2 = ws + 768;  float* shift2 = ws + 896;
    float* c2v    = ws + 1024; float* crb    = ws + 1152;     // fold constants
    short* W1lp = (short*)(ws + 1536);                        // 4096 f
    short* W1rp = (short*)(ws + 1536 + 4096);                 // 4096 f
    short* W2lp = (short*)(ws + 1536 + 8192);                 // 8192 f
    short* W2rp = (short*)(ws + 1536 + 16384);                // 8192 f
    int*   deg    = (int*)(ws + 26112);                       // N
    int*   part   = deg + N;                                  // N
    int*   bsum   = part + N;                                 // 1024
    int*   rowptr = bsum + 1024;                              // N+1
    int*   cursor = rowptr + (N + 1024);                      // N (padded)
    float* degf   = (float*)(cursor + N);                     // N
    int*   ssrc   = (int*)(degf + N);                         // E
    unsigned short* t1   = (unsigned short*)(ssrc + E);       // N*128 bf16
    unsigned short* aggb = t1 + (size_t)N * F_H;              // N*128 bf16

    // ---- Graph build + layer-1 weight pack ----
    hipMemsetAsync(ws, 0, 1024 * sizeof(float), stream);      // stats
    hipMemsetAsync(deg, 0, (size_t)N * sizeof(int), stream);
    pack_weights_kernel<<<4, 256, 0, stream>>>(W1l, nullptr, W1lp, 2);
    pack_weights_kernel<<<4, 256, 0, stream>>>(W1r, nullptr, W1rp, 2);
    hist_kernel<<<(E + 255) / 256, 256, 0, stream>>>(ei, deg, E);
    scan1_kernel<<<NB1, 256, 0, stream>>>(deg, part, bsum, N);
    scan2_kernel<<<1, 256, 0, stream>>>(bsum, NB1);
    scan3_kernel<<<(N + 255) / 256, 256, 0, stream>>>(part, bsum, deg, rowptr,
                                                      cursor, degf, N, E);
    fill_kernel<<<(E + 255) / 256, 256, 0, stream>>>(ei, cursor, ssrc, E);

    // ---- Layer 1 ----
    gather1_kernel<<<N / 16, 256, 0, stream>>>(x, rowptr, ssrc, aggb);
    gemm_mfma_kernel<F_IN, false><<<N / 64, 256, 0, stream>>>(
        aggb, x, nullptr, W1lp, W1rp, b1, nullptr, nullptr,
        nullptr, t1, gsum1, gsq1);
    bn_finalize_kernel<<<1, 128, 0, stream>>>(gsum1, gsq1, g1, be1,
                                              scale1, shift1, 1.f / N);

    // ---- Layer 2 (BN1 folded: scale1 into weights, shift1 into c2/crb) ----
    pack_weights_kernel<<<8, 256, 0, stream>>>(W2l, scale1, W2lp, 4);
    pack_weights_kernel<<<8, 256, 0, stream>>>(W2r, scale1, W2rp, 4);
    bn_fold_kernel<<<1, 128, 0, stream>>>(shift1, W2l, W2r, b2, c2v, crb);
    gather2_kernel<<<N / 16, 256, 0, stream>>>(t1, rowptr, ssrc, aggb);
    gemm_mfma_kernel<F_H, true><<<N / 64, 256, 0, stream>>>(
        aggb, nullptr, t1, W2lp, W2rp, crb, c2v, degf,
        out, nullptr, gsum2, gsq2);
    bn_finalize_kernel<<<1, 128, 0, stream>>>(gsum2, gsq2, g2, be2,
                                              scale2, shift2, 1.f / N);
    bn_apply_relu_kernel<<<(N * F_H / 4 + 255) / 256, 256, 0, stream>>>(
        out, scale2, shift2, N * F_H / 4);
}

// Round 5
// 632.894 us; speedup vs baseline: 3.7093x; 1.1032x over previous
//
#include <hip/hip_runtime.h>

#define N_NODES 200000
#define N_EDGES 1200000
#define F_IN    64
#define F_H     128
#define BN_EPS  1e-5f

typedef short bf16x8 __attribute__((ext_vector_type(8)));   // 8 bf16 in 4 VGPRs
typedef float f32x4  __attribute__((ext_vector_type(4)));
typedef unsigned short us4 __attribute__((ext_vector_type(4)));

__device__ __forceinline__ unsigned short f2bf(float f) {
    union { float f; unsigned u; } v; v.f = f;
    unsigned r = (v.u + 0x7FFFu + ((v.u >> 16) & 1u)) >> 16;  // RNE
    return (unsigned short)r;
}
__device__ __forceinline__ float bf2f(unsigned short b) {
    union { unsigned u; float f; } v; v.u = ((unsigned)b) << 16;
    return v.f;
}

// ---------------------------------------------------------------------------
// Weight pack into bf16 MFMA B-fragment order for mfma_f32_16x16x32_bf16:
// element j of lane L in (nt,kt) tile = W[kt*32+(L>>4)*8+j][nt*16+(L&15)],
// optionally pre-scaled per-k (folds BN1 scale into layer-2 weights).
// ---------------------------------------------------------------------------
__global__ void pack_weights_kernel(const float* __restrict__ W,
                                    const float* __restrict__ kscale,
                                    short* __restrict__ P, int KT)
{
    int t = blockIdx.x * 256 + threadIdx.x;            // over 8*KT*64
    if (t >= 8 * KT * 64) return;
    int lane = t & 63;
    int kt   = (t >> 6) % KT;
    int nt   = t / (64 * KT);
    int k0   = kt * 32 + (lane >> 4) * 8;
    int n    = nt * 16 + (lane & 15);
#pragma unroll
    for (int j = 0; j < 8; ++j) {
        float w = W[(size_t)(k0 + j) * 128 + n];
        if (kscale) w *= kscale[k0 + j];
        P[(size_t)t * 8 + j] = (short)f2bf(w);
    }
}

// ---------------------------------------------------------------------------
// CSR build: histogram -> 2-level exclusive scan -> cursor fill
// ---------------------------------------------------------------------------
__global__ __launch_bounds__(256) void hist_kernel(const int* __restrict__ ei,
                                                   int* __restrict__ deg, int E)
{
    int e = blockIdx.x * 256 + threadIdx.x;
    if (e < E) atomicAdd(&deg[ei[E + e]], 1);
}

__global__ __launch_bounds__(256) void scan1_kernel(const int* __restrict__ deg,
        int* __restrict__ part, int* __restrict__ bsum, int n)
{
    __shared__ int s[256];
    int t = threadIdx.x;
    int base = blockIdx.x * 1024 + t * 4;
    int v[4];
#pragma unroll
    for (int j = 0; j < 4; ++j) v[j] = (base + j < n) ? deg[base + j] : 0;
    int tsum = v[0] + v[1] + v[2] + v[3];
    s[t] = tsum;
    __syncthreads();
    for (int off = 1; off < 256; off <<= 1) {
        int xv = (t >= off) ? s[t - off] : 0;
        __syncthreads();
        s[t] += xv;
        __syncthreads();
    }
    int excl = s[t] - tsum;
#pragma unroll
    for (int j = 0; j < 4; ++j) {
        if (base + j < n) part[base + j] = excl;
        excl += v[j];
    }
    if (t == 255) bsum[blockIdx.x] = s[255];
}

__global__ void scan2_kernel(int* __restrict__ bsum, int nb)
{
    __shared__ int s[256];
    int t = threadIdx.x;
    int v = (t < nb) ? bsum[t] : 0;
    s[t] = v;
    __syncthreads();
    for (int off = 1; off < 256; off <<= 1) {
        int xv = (t >= off) ? s[t - off] : 0;
        __syncthreads();
        s[t] += xv;
        __syncthreads();
    }
    if (t < nb) bsum[t] = s[t] - v;   // exclusive
}

__global__ __launch_bounds__(256) void scan3_kernel(
    const int* __restrict__ part, const int* __restrict__ bsum,
    const int* __restrict__ deg, int* __restrict__ rowptr,
    int* __restrict__ cursor, float* __restrict__ degf, int n, int E)
{
    int i = blockIdx.x * 256 + threadIdx.x;
    if (i == 0) rowptr[n] = E;
    if (i >= n) return;
    int r = part[i] + bsum[i >> 10];
    rowptr[i] = r;
    cursor[i] = r;
    degf[i]   = (float)deg[i];
}

__global__ __launch_bounds__(256) void fill_kernel(const int* __restrict__ ei,
        int* __restrict__ cursor, int* __restrict__ ssrc, int E)
{
    int e = blockIdx.x * 256 + threadIdx.x;
    if (e >= E) return;
    int d = ei[E + e];
    int pos = atomicAdd(&cursor[d], 1);
    ssrc[pos] = ei[e];
}

// ---------------------------------------------------------------------------
// Gather-aggregate layer 1: aggb[row,0:64] = bf16( sum_src x[src,:] ).
// 4 rows per wave + software-pipelined ssrc prefetch.
// ---------------------------------------------------------------------------
__global__ __launch_bounds__(256) void gather1_kernel(
    const float* __restrict__ x, const int* __restrict__ rowptr,
    const int* __restrict__ ssrc, unsigned short* __restrict__ aggb)
{
    const int tid  = threadIdx.x;
    const int wv   = tid >> 6;
    const int lane = tid & 63;
    const int sub  = lane >> 4;
    const int li   = lane & 15;
    const int row  = blockIdx.x * 16 + wv * 4 + sub;

    int b = rowptr[row], e = rowptr[row + 1];
    float4 acc = {0.f, 0.f, 0.f, 0.f};
    if (b < e) {
        int s = ssrc[b];
        for (int j = b; j < e; ++j) {
            int sn = (j + 1 < e) ? ssrc[j + 1] : 0;   // prefetch next index
            float4 v = ((const float4*)(x + (size_t)s * F_IN))[li];
            acc.x += v.x; acc.y += v.y; acc.z += v.z; acc.w += v.w;
            s = sn;
        }
    }
    us4 o;
    o.x = f2bf(acc.x); o.y = f2bf(acc.y); o.z = f2bf(acc.z); o.w = f2bf(acc.w);
    *(us4*)(aggb + (size_t)row * F_IN + li * 4) = o;
}

// ---------------------------------------------------------------------------
// Gather-aggregate layer 2: aggb[row,0:128] = bf16( sum_src t1[src,:] ).
// ---------------------------------------------------------------------------
__global__ __launch_bounds__(256) void gather2_kernel(
    const unsigned short* __restrict__ t1, const int* __restrict__ rowptr,
    const int* __restrict__ ssrc, unsigned short* __restrict__ aggb)
{
    const int tid  = threadIdx.x;
    const int wv   = tid >> 6;
    const int lane = tid & 63;
    const int sub  = lane >> 4;
    const int li   = lane & 15;
    const int row  = blockIdx.x * 16 + wv * 4 + sub;

    int b = rowptr[row], e = rowptr[row + 1];
    float acc[8] = {};
    if (b < e) {
        int s = ssrc[b];
        for (int j = b; j < e; ++j) {
            int sn = (j + 1 < e) ? ssrc[j + 1] : 0;
            bf16x8 v = *(const bf16x8*)(t1 + (size_t)s * F_H + li * 8);
#pragma unroll
            for (int k = 0; k < 8; ++k) acc[k] += bf2f((unsigned short)v[k]);
            s = sn;
        }
    }
    bf16x8 o;
#pragma unroll
    for (int k = 0; k < 8; ++k) o[k] = (short)f2bf(acc[k]);
    *(bf16x8*)(aggb + (size_t)row * F_H + li * 8) = o;
}

// ---------------------------------------------------------------------------
// MFMA GEMM, persistent row-tile version.
// Block = 4 waves. Weights (Wl+Wr, fragment order) staged once into LDS.
// Each block grid-strides over 256-row tiles; each wave owns 64 rows =
// 4 A-subtiles of 16 rows. Per k-step per wave: 8 global loads +
// 16 ds_read_b128 + 64 MFMA (4 independent subtile chains).
// Stats accumulate in registers across tiles -> one LDS reduce + 128
// global atomics per block.
// L1: out = relu(A@W1l + b1 + X@W1r), X fp32 -> t1 bf16.
// L2: out = relu(A@W2l' + Xb@W2r' + crb + deg*c2), Xb bf16, out fp32.
// ---------------------------------------------------------------------------
template<int K, bool L2>
__global__ __launch_bounds__(256) void gemm_mfma_kernel(
    const unsigned short* __restrict__ Ab,
    const float* __restrict__ Xf,
    const unsigned short* __restrict__ Xb,
    const short* __restrict__ Wlp, const short* __restrict__ Wrp,
    const float* __restrict__ bias,
    const float* __restrict__ c2, const float* __restrict__ degf,
    float* __restrict__ outF, unsigned short* __restrict__ outB,
    float* __restrict__ gsum, float* __restrict__ gsq, int nTiles)
{
    constexpr int KT = K / 32;
    constexpr int CH = K * 16;            // bf16x8 chunks per weight matrix
    __shared__ bf16x8 wlds[2 * CH];       // Wl | Wr
    __shared__ float sS[128];
    __shared__ float sQ[128];

    const int tid  = threadIdx.x;
    const int lane = tid & 63;
    const int wv   = tid >> 6;
    const int m    = lane & 15;
    const int quad = lane >> 4;
    const int col_l = m;

    // ---- stage weights into LDS (coalesced b128 copies) ----
    {
        const bf16x8* s1 = (const bf16x8*)Wlp;
        const bf16x8* s2 = (const bf16x8*)Wrp;
        for (int i = tid; i < CH; i += 256) wlds[i] = s1[i];
        for (int i = tid; i < CH; i += 256) wlds[CH + i] = s2[i];
    }
    if (tid < 128) { sS[tid] = 0.f; sQ[tid] = 0.f; }
    __syncthreads();

    // per-nt epilogue constants
    float bcol[8], ccol[8];
#pragma unroll
    for (int nt = 0; nt < 8; ++nt) {
        bcol[nt] = bias[nt * 16 + col_l];
        if constexpr (L2) ccol[nt] = c2[nt * 16 + col_l];
    }

    float stS[8] = {}, stQ[8] = {};

    for (int tile = blockIdx.x; tile < nTiles; tile += gridDim.x) {
        const int rowbase = tile * 256 + wv * 64;
        f32x4 acc[4][8] = {};

#pragma unroll
        for (int kt = 0; kt < KT; ++kt) {
            const int k0 = kt * 32 + quad * 8;
            bf16x8 af[4], xf[4];
#pragma unroll
            for (int st = 0; st < 4; ++st) {
                int r  = rowbase + st * 16 + m;
                int rc = r < N_NODES ? r : N_NODES - 1;
                af[st] = *(const bf16x8*)(Ab + (size_t)rc * K + k0);
                if constexpr (L2) {
                    xf[st] = *(const bf16x8*)(Xb + (size_t)rc * K + k0);
                } else {
                    const float4* xp = (const float4*)(Xf + (size_t)rc * K + k0);
                    float4 x0 = xp[0], x1 = xp[1];
                    xf[st][0] = (short)f2bf(x0.x); xf[st][1] = (short)f2bf(x0.y);
                    xf[st][2] = (short)f2bf(x0.z); xf[st][3] = (short)f2bf(x0.w);
                    xf[st][4] = (short)f2bf(x1.x); xf[st][5] = (short)f2bf(x1.y);
                    xf[st][6] = (short)f2bf(x1.z); xf[st][7] = (short)f2bf(x1.w);
                }
            }
#pragma unroll
            for (int nt = 0; nt < 8; ++nt) {
                bf16x8 wl = wlds[(nt * KT + kt) * 64 + lane];
#pragma unroll
                for (int st = 0; st < 4; ++st)
                    acc[st][nt] = __builtin_amdgcn_mfma_f32_16x16x32_bf16(
                        af[st], wl, acc[st][nt], 0, 0, 0);
                bf16x8 wr = wlds[CH + (nt * KT + kt) * 64 + lane];
#pragma unroll
                for (int st = 0; st < 4; ++st)
                    acc[st][nt] = __builtin_amdgcn_mfma_f32_16x16x32_bf16(
                        xf[st], wr, acc[st][nt], 0, 0, 0);
            }
        }

        // ---- epilogue: C/D layout col = lane&15, row = quad*4 + reg ----
#pragma unroll
        for (int st = 0; st < 4; ++st) {
            const int orow = rowbase + st * 16 + quad * 4;
            float dg[4];
            if constexpr (L2) {
#pragma unroll
                for (int r = 0; r < 4; ++r) {
                    int rr = orow + r;
                    dg[r] = (rr < N_NODES) ? degf[rr] : 0.f;
                }
            }
#pragma unroll
            for (int nt = 0; nt < 8; ++nt) {
                int col = nt * 16 + col_l;
#pragma unroll
                for (int r = 0; r < 4; ++r) {
                    int rr = orow + r;
                    if (rr < N_NODES) {
                        float base = L2 ? fmaf(dg[r], ccol[nt], bcol[nt]) : bcol[nt];
                        float v = fmaxf(acc[st][nt][r] + base, 0.f);
                        if constexpr (L2) outF[(size_t)rr * 128 + col] = v;
                        else              outB[(size_t)rr * 128 + col] = f2bf(v);
                        stS[nt] += v;
                        stQ[nt] = fmaf(v, v, stQ[nt]);
                    }
                }
            }
        }
    }

    // ---- stats reduce: registers -> LDS -> global ----
#pragma unroll
    for (int nt = 0; nt < 8; ++nt) {
        atomicAdd(&sS[nt * 16 + col_l], stS[nt]);
        atomicAdd(&sQ[nt * 16 + col_l], stQ[nt]);
    }
    __syncthreads();
    if (tid < 128) {
        atomicAdd(&gsum[tid], sS[tid]);
        atomicAdd(&gsq[tid],  sQ[tid]);
    }
}

// ---------------------------------------------------------------------------
// BN finalize: per-feature scale/shift.
// ---------------------------------------------------------------------------
__global__ void bn_finalize_kernel(
    const float* __restrict__ gsum, const float* __restrict__ gsq,
    const float* __restrict__ g, const float* __restrict__ be,
    float* __restrict__ scale, float* __restrict__ shift, float invN)
{
    int c = threadIdx.x;  // 128
    float mean = gsum[c] * invN;
    float var  = fmaxf(gsq[c] * invN - mean * mean, 0.f);
    float sc   = g[c] * rsqrtf(var + BN_EPS);
    scale[c] = sc;
    shift[c] = be[c] - mean * sc;
}

// BN1 fold constants: c2 = shift1@W2l ; crb = shift1@W2r + b2
__global__ void bn_fold_kernel(
    const float* __restrict__ shift1, const float* __restrict__ W2l,
    const float* __restrict__ W2r, const float* __restrict__ b2,
    float* __restrict__ c2, float* __restrict__ crb)
{
    int col = threadIdx.x;  // 128
    float a = 0.f, r = 0.f;
    for (int k = 0; k < 128; ++k) {
        float s = shift1[k];
        a = fmaf(s, W2l[(size_t)k * 128 + col], a);
        r = fmaf(s, W2r[(size_t)k * 128 + col], r);
    }
    c2[col]  = a;
    crb[col] = r + b2[col];
}

// ---------------------------------------------------------------------------
// Final BN apply + ReLU (in place on d_out).
// ---------------------------------------------------------------------------
__global__ __launch_bounds__(256) void bn_apply_relu_kernel(
    float* __restrict__ h, const float* __restrict__ scale,
    const float* __restrict__ shift, int n4)
{
    int i = blockIdx.x * 256 + threadIdx.x;
    if (i >= n4) return;
    int cb = i & 31;
    float4 v  = ((float4*)h)[i];
    float4 sc = ((const float4*)scale)[cb];
    float4 sh = ((const float4*)shift)[cb];
    v.x = fmaxf(fmaf(v.x, sc.x, sh.x), 0.f);
    v.y = fmaxf(fmaf(v.y, sc.y, sh.y), 0.f);
    v.z = fmaxf(fmaf(v.z, sc.z, sh.z), 0.f);
    v.w = fmaxf(fmaf(v.w, sc.w, sh.w), 0.f);
    ((float4*)h)[i] = v;
}

extern "C" void kernel_launch(void* const* d_in, const int* in_sizes, int n_in,
                              void* d_out, int out_size, void* d_ws, size_t ws_size,
                              hipStream_t stream) {
    const float* x   = (const float*)d_in[0];
    const int*   ei  = (const int*)d_in[1];
    const float* W1l = (const float*)d_in[2];
    const float* b1  = (const float*)d_in[3];
    const float* W1r = (const float*)d_in[4];
    const float* g1  = (const float*)d_in[5];
    const float* be1 = (const float*)d_in[6];
    const float* W2l = (const float*)d_in[7];
    const float* b2  = (const float*)d_in[8];
    const float* W2r = (const float*)d_in[9];
    const float* g2  = (const float*)d_in[10];
    const float* be2 = (const float*)d_in[11];
    float* out = (float*)d_out;

    const int N = N_NODES, E = N_EDGES;
    const int NB1 = (N + 1023) / 1024;          // 196 scan blocks
    const int nTiles = (N + 255) / 256;         // 782 row-tiles

    // Workspace layout (float units):
    float* ws     = (float*)d_ws;
    float* gsum1  = ws;        float* gsq1   = ws + 128;
    float* gsum2  = ws + 256;  float* gsq2   = ws + 384;
    float* scale1 = ws + 512;  float* shift1 = ws + 640;
    float* scale2 = ws + 768;  float* shift2 = ws + 896;
    float* c2v    = ws + 1024; float* crb    = ws + 1152;     // fold constants
    short* W1lp = (short*)(ws + 1536);                        // 4096 f
    short* W1rp = (short*)(ws + 1536 + 4096);                 // 4096 f
    short* W2lp = (short*)(ws + 1536 + 8192);                 // 8192 f
    short* W2rp = (short*)(ws + 1536 + 16384);                // 8192 f
    int*   deg    = (int*)(ws + 26112);                       // N
    int*   part   = deg + N;                                  // N
    int*   bsum   = part + N;                                 // 1024
    int*   rowptr = bsum + 1024;                              // N+1
    int*   cursor = rowptr + (N + 1024);                      // N (padded)
    float* degf   = (float*)(cursor + N);                     // N
    int*   ssrc   = (int*)(degf + N);                         // E
    unsigned short* t1   = (unsigned short*)(ssrc + E);       // N*128 bf16
    unsigned short* aggb = t1 + (size_t)N * F_H;              // N*128 bf16

    // ---- Graph build + layer-1 weight pack ----
    hipMemsetAsync(ws, 0, 1024 * sizeof(float), stream);      // stats
    hipMemsetAsync(deg, 0, (size_t)N * sizeof(int), stream);
    pack_weights_kernel<<<4, 256, 0, stream>>>(W1l, nullptr, W1lp, 2);
    pack_weights_kernel<<<4, 256, 0, stream>>>(W1r, nullptr, W1rp, 2);
    hist_kernel<<<(E + 255) / 256, 256, 0, stream>>>(ei, deg, E);
    scan1_kernel<<<NB1, 256, 0, stream>>>(deg, part, bsum, N);
    scan2_kernel<<<1, 256, 0, stream>>>(bsum, NB1);
    scan3_kernel<<<(N + 255) / 256, 256, 0, stream>>>(part, bsum, deg, rowptr,
                                                      cursor, degf, N, E);
    fill_kernel<<<(E + 255) / 256, 256, 0, stream>>>(ei, cursor, ssrc, E);

    // ---- Layer 1 ----
    gather1_kernel<<<N / 16, 256, 0, stream>>>(x, rowptr, ssrc, aggb);
    gemm_mfma_kernel<F_IN, false><<<512, 256, 0, stream>>>(
        aggb, x, nullptr, W1lp, W1rp, b1, nullptr, nullptr,
        nullptr, t1, gsum1, gsq1, nTiles);
    bn_finalize_kernel<<<1, 128, 0, stream>>>(gsum1, gsq1, g1, be1,
                                              scale1, shift1, 1.f / N);

    // ---- Layer 2 (BN1 folded: scale1 into weights, shift1 into c2/crb) ----
    pack_weights_kernel<<<8, 256, 0, stream>>>(W2l, scale1, W2lp, 4);
    pack_weights_kernel<<<8, 256, 0, stream>>>(W2r, scale1, W2rp, 4);
    bn_fold_kernel<<<1, 128, 0, stream>>>(shift1, W2l, W2r, b2, c2v, crb);
    gather2_kernel<<<N / 16, 256, 0, stream>>>(t1, rowptr, ssrc, aggb);
    gemm_mfma_kernel<F_H, true><<<512, 256, 0, stream>>>(
        aggb, nullptr, t1, W2lp, W2rp, crb, c2v, degf,
        out, nullptr, gsum2, gsq2, nTiles);
    bn_finalize_kernel<<<1, 128, 0, stream>>>(gsum2, gsq2, g2, be2,
                                              scale2, shift2, 1.f / N);
    bn_apply_relu_kernel<<<(N * F_H / 4 + 255) / 256, 256, 0, stream>>>(
        out, scale2, shift2, N * F_H / 4);
}